// Round 1
// baseline (1753.753 us; speedup 1.0000x reference)
//
#include <hip/hip_runtime.h>
#include <math.h>

// DeepGESN: 2 layers of h = tanh(wiu + L @ (h @ W_hh^T)), 10 iters each.
// Rewrite: L@(h@W) == (L@h)@W  -> big matmul consumes h directly, small 64x64
// projection + tanh fused as a row-local epilogue. One kernel per iteration.
//
// N=4096, H=64, f32 everywhere (no fp32 MFMA on CDNA4 -> vector ALU baseline).

#define NN 4096
#define HH 64

// ---------------------------------------------------------------------------
// Kernel A: wiu = x @ W_ih^T ; h = tanh(wiu)   (iteration 1, since h0 = 0)
// grid 1024 x 256 : 4 rows per block, 1 output/thread
// ---------------------------------------------------------------------------
__global__ __launch_bounds__(256) void gesn_input_kernel(
    const float* __restrict__ x,     // [N,64]
    const float* __restrict__ W,     // [64,64]  (W_ih, row-major [out][in])
    float* __restrict__ wiu,         // [N,64]
    float* __restrict__ h)           // [N,64]
{
    __shared__ float W_lds[64 * 65];   // pad 65 -> bank (j+k)%32, conflict-free
    __shared__ float x_lds[256];
    const int t = threadIdx.x;

    // cooperative W load: 16 consecutive elems/thread (scalar LDS writes, once)
    {
        const int j  = t >> 2;
        const int k0 = (t & 3) << 4;
#pragma unroll
        for (int q = 0; q < 16; ++q)
            W_lds[j * 65 + k0 + q] = W[j * 64 + k0 + q];
    }
    const int i0 = blockIdx.x * 4;     // 4 rows, contiguous 256 floats
    x_lds[t] = x[i0 * 64 + t];
    __syncthreads();

    const int j = t & 63;
    const int i = t >> 6;
    float z = 0.f;
#pragma unroll
    for (int k = 0; k < 64; ++k)
        z = fmaf(x_lds[i * 64 + k], W_lds[j * 65 + k], z);

    const int gidx = (i0 + i) * 64 + j;
    wiu[gidx] = z;
    h[gidx]   = tanhf(z);
}

// ---------------------------------------------------------------------------
// Kernel B: h_out = tanh(wiu + (L @ h_in) @ W_hh^T)
// grid 256 x 256 : 16 rows/block (1 block per CU), thread owns 2x2 of G.
// K-loop: 64 chunks of 64; stage h-chunk [64][64] + L-tile [16][64] in LDS.
// Epilogue: G -> LDS, then z = wiu + G@W^T per (row, col j) + tanh.
// Optionally also writes the strided final output (last iteration).
// ---------------------------------------------------------------------------
__global__ __launch_bounds__(256) void gesn_iter_kernel(
    const float* __restrict__ L,      // [4096,4096]
    const float* __restrict__ h_in,   // [4096,64]
    const float* __restrict__ wiu,    // [4096,64]
    const float* __restrict__ W,      // W_hh [64,64]
    float* __restrict__ h_out,        // [4096,64]
    float* __restrict__ out2,         // nullptr, or [4096,128] strided output
    int out_col0)
{
    __shared__ float h_lds[64 * 64];      // 16 KiB, flat chunk copy (stride 64)
    __shared__ float L_lds[16 * 68];      // pad 68: bank (4r+kk)%32 over r
    __shared__ float G_lds[16 * 68];
    __shared__ float W_lds[64 * 65];

    const int t = threadIdx.x;

    // W_hh load once (needed only at epilogue; loop barriers cover the sync)
    {
        const int j  = t >> 2;
        const int k0 = (t & 3) << 4;
#pragma unroll
        for (int q = 0; q < 16; ++q)
            W_lds[j * 65 + k0 + q] = W[j * 64 + k0 + q];
    }

    const int r0 = blockIdx.x * 16;        // global row base

    // main-loop decomposition: rows 2p,2p+1 ; cols c0,c0+1
    const int p  = t >> 5;                 // 0..7
    const int c0 = (t & 31) * 2;           // 0,2,..,62
    float acc00 = 0.f, acc01 = 0.f, acc10 = 0.f, acc11 = 0.f;

    // L staging decomposition: one float4 per thread
    const int lr = t >> 4;                 // 0..15
    const int lc = (t & 15) * 4;

    for (int kb = 0; kb < 64; ++kb) {
        __syncthreads();                   // previous chunk's readers done
        // stage L tile [16][64] -> [16][68]
        const float4 lv = *reinterpret_cast<const float4*>(
            &L[(size_t)(r0 + lr) * 4096 + kb * 64 + lc]);
        *reinterpret_cast<float4*>(&L_lds[lr * 68 + lc]) = lv;
        // stage h chunk: rows kb*64..+63 are 4096 contiguous floats
        const float4* hsrc = reinterpret_cast<const float4*>(h_in + kb * 4096);
        float4* hdst = reinterpret_cast<float4*>(h_lds);
#pragma unroll
        for (int q = 0; q < 4; ++q)
            hdst[t + 256 * q] = hsrc[t + 256 * q];
        __syncthreads();

#pragma unroll
        for (int kk = 0; kk < 64; ++kk) {
            const float  lv0 = L_lds[(2 * p) * 68 + kk];
            const float  lv1 = L_lds[(2 * p + 1) * 68 + kk];
            const float2 hv  = *reinterpret_cast<const float2*>(&h_lds[kk * 64 + c0]);
            acc00 = fmaf(lv0, hv.x, acc00);
            acc01 = fmaf(lv0, hv.y, acc01);
            acc10 = fmaf(lv1, hv.x, acc10);
            acc11 = fmaf(lv1, hv.y, acc11);
        }
    }

    // G -> LDS
    G_lds[(2 * p) * 68 + c0]         = acc00;
    G_lds[(2 * p) * 68 + c0 + 1]     = acc01;
    G_lds[(2 * p + 1) * 68 + c0]     = acc10;
    G_lds[(2 * p + 1) * 68 + c0 + 1] = acc11;
    __syncthreads();

    // epilogue: z = wiu + G @ W^T ; h = tanh(z)
    const int j  = t & 63;                 // col, = lane -> W_lds conflict-free
    const int iw = t >> 6;                 // wave id: G_lds row broadcast
#pragma unroll
    for (int rr = 0; rr < 4; ++rr) {
        const int i = iw * 4 + rr;         // 0..15
        float z = wiu[(size_t)(r0 + i) * 64 + j];
#pragma unroll
        for (int m = 0; m < 64; ++m)
            z = fmaf(G_lds[i * 68 + m], W_lds[j * 65 + m], z);
        const float hv = tanhf(z);
        h_out[(size_t)(r0 + i) * 64 + j] = hv;
        if (out2) out2[(size_t)(r0 + i) * 128 + out_col0 + j] = hv;
    }
}

// ---------------------------------------------------------------------------
extern "C" void kernel_launch(void* const* d_in, const int* in_sizes, int n_in,
                              void* d_out, int out_size, void* d_ws, size_t ws_size,
                              hipStream_t stream) {
    const float* X    = (const float*)d_in[0];
    const float* L    = (const float*)d_in[1];
    const float* Wih0 = (const float*)d_in[2];
    const float* Whh0 = (const float*)d_in[3];
    const float* Wih1 = (const float*)d_in[4];
    const float* Whh1 = (const float*)d_in[5];
    float* out = (float*)d_out;

    char* ws   = (char*)d_ws;
    float* wiu = (float*)(ws);                       // 1 MiB
    float* hA  = (float*)(ws + (1u << 20));          // 1 MiB
    float* hB  = (float*)(ws + (2u << 20));          // 1 MiB

    for (int layer = 0; layer < 2; ++layer) {
        const float* x   = layer ? hB : X;           // layer1 input = layer0 final h
        const float* Wih = layer ? Wih1 : Wih0;
        const float* Whh = layer ? Whh1 : Whh0;

        // iteration 1: wiu + tanh(wiu)
        gesn_input_kernel<<<1024, 256, 0, stream>>>(x, Wih, wiu, hA);

        // iterations 2..10
        float* cur = hA;
        float* nxt = hB;
        for (int it = 0; it < 9; ++it) {
            float* o2 = (it == 8) ? out : nullptr;   // fuse final strided write
            gesn_iter_kernel<<<256, 256, 0, stream>>>(L, cur, wiu, Whh, nxt,
                                                      o2, layer * 64);
            float* tmp = cur; cur = nxt; nxt = tmp;
        }
        // 9 iterations (odd) -> final h lives in hB
    }
}

// Round 2
// 652.529 us; speedup vs baseline: 2.6876x; 2.6876x over previous
//
#include <hip/hip_runtime.h>
#include <hip/hip_bf16.h>
#include <math.h>

// DeepGESN: 2 layers of h = tanh(wiu + L @ (h @ W_hh^T)), 10 iters each.
// Rewrite: L@(h@W) == (L@h)@W. Big matmul G=L@h done in bf16 MFMA with
// two-term error-compensated splitting (L=Lhi+Llo, h=hhi+hlo, 3 products
// -> ~2^-18 relative operand error ~ f32-class final error). Small 64x64
// projection + tanh stays f32 on VALU in the post kernel.
//
// Layouts (packed at split time so all MFMA fragment loads are lane-linear
// coalesced dwordx4):
//  Apack[rb][kb][l][8]: rb=16-row block (256), kb=32-k block (128), l=lane.
//      value = L[rb*16 + (l&15)][kb*32 + 8*(l>>4) + j]    (bf16 bits)
//  Bpack[kb][cf][l][8]: cf=16-col frag (4).
//      value = h[kb*32 + 8*(l>>4) + j][cf*16 + (l&15)]
// mfma_f32_16x16x32_bf16: A lane l holds A[l&15][8*(l>>4)+j];
//   B lane l holds B[8*(l>>4)+j][l&15]; D[(l>>4)*4+r][l&15] (m89/m91).

#define NN 4096
#define HH 64

typedef float  f32x4  __attribute__((ext_vector_type(4)));
typedef short  bf16x8 __attribute__((ext_vector_type(8)));

static __device__ __forceinline__ unsigned short bf16_bits(__hip_bfloat16 b) {
    union { __hip_bfloat16 b; unsigned short u; } cv; cv.b = b; return cv.u;
}

// ---------------------------------------------------------------------------
// Split + pack L (f32 [4096][4096]) -> Ahi/Alo (bf16 fragment-linear, 32MB ea)
// grid 8192: rb = bid>>5 (256), kg = bid&31 (128-k group)
// ---------------------------------------------------------------------------
__global__ __launch_bounds__(256) void convert_L(
    const float* __restrict__ L, short* __restrict__ Ahi, short* __restrict__ Alo)
{
    __shared__ float T[16 * 132];
    const int t  = threadIdx.x;
    const int rb = blockIdx.x >> 5;
    const int kg = blockIdx.x & 31;

    // coalesced stage: 16 rows x 128 floats
    {
        const int row = t >> 4;
        const int c4  = (t & 15) * 4;
        const float* src = L + (size_t)(rb * 16 + row) * NN + kg * 128;
        float4 v0 = *reinterpret_cast<const float4*>(src + c4);
        float4 v1 = *reinterpret_cast<const float4*>(src + c4 + 64);
        *reinterpret_cast<float4*>(&T[row * 132 + c4])      = v0;
        *reinterpret_cast<float4*>(&T[row * 132 + c4 + 64]) = v1;
    }
    __syncthreads();

    const int kbl = t >> 6;            // 0..3 local 32-k block
    const int l   = t & 63;
    const int r   = l & 15, g = l >> 4;
    short hi8[8], lo8[8];
#pragma unroll
    for (int j = 0; j < 8; ++j) {
        const float v = T[r * 132 + kbl * 32 + g * 8 + j];
        __hip_bfloat16 bh = __float2bfloat16(v);
        const float vh = __bfloat162float(bh);
        __hip_bfloat16 bl = __float2bfloat16(v - vh);
        hi8[j] = (short)bf16_bits(bh);
        lo8[j] = (short)bf16_bits(bl);
    }
    const size_t off = ((size_t)(rb * 128 + kg * 4 + kbl) * 64 + l) * 8;
    *reinterpret_cast<bf16x8*>(Ahi + off) = *reinterpret_cast<bf16x8*>(hi8);
    *reinterpret_cast<bf16x8*>(Alo + off) = *reinterpret_cast<bf16x8*>(lo8);
}

// ---------------------------------------------------------------------------
// MFMA matmul: Gp[s] rows p*128..+127 = (L @ h) partial over K=512.
// grid 256 = 32 row-panels x 8 K-splits. 4 waves x 32 rows. No LDS/barriers.
// 3 products: Ahi*Bhi + Ahi*Blo + Alo*Bhi  (error-compensated bf16)
// ---------------------------------------------------------------------------
__global__ __launch_bounds__(256) void gesn_mm(
    const short* __restrict__ Ahi, const short* __restrict__ Alo,
    const short* __restrict__ Bhi, const short* __restrict__ Blo,
    float* __restrict__ Gp)            // [8][4096][64]
{
    const int t = threadIdx.x;
    const int w = t >> 6, l = t & 63;
    const int p = blockIdx.x >> 3;     // row-panel (128 rows)
    const int s = blockIdx.x & 7;      // K-split
    const int rb0 = p * 8 + w * 2;     // this wave: 16-row blocks rb0, rb0+1
    const int kb0 = s * 16;

    f32x4 acc[2][4] = {};

    for (int kbl = 0; kbl < 16; ++kbl) {
        const int kb = kb0 + kbl;
        bf16x8 aH[2], aL[2], bH[4], bL[4];
#pragma unroll
        for (int rf = 0; rf < 2; ++rf) {
            const size_t ao = ((size_t)((rb0 + rf) * 128 + kb) * 64 + l) * 8;
            aH[rf] = *reinterpret_cast<const bf16x8*>(Ahi + ao);
            aL[rf] = *reinterpret_cast<const bf16x8*>(Alo + ao);
        }
#pragma unroll
        for (int cf = 0; cf < 4; ++cf) {
            const size_t bo = ((size_t)(kb * 4 + cf) * 64 + l) * 8;
            bH[cf] = *reinterpret_cast<const bf16x8*>(Bhi + bo);
            bL[cf] = *reinterpret_cast<const bf16x8*>(Blo + bo);
        }
#pragma unroll
        for (int rf = 0; rf < 2; ++rf)
#pragma unroll
            for (int cf = 0; cf < 4; ++cf) {
                acc[rf][cf] = __builtin_amdgcn_mfma_f32_16x16x32_bf16(
                    aH[rf], bH[cf], acc[rf][cf], 0, 0, 0);
                acc[rf][cf] = __builtin_amdgcn_mfma_f32_16x16x32_bf16(
                    aH[rf], bL[cf], acc[rf][cf], 0, 0, 0);
                acc[rf][cf] = __builtin_amdgcn_mfma_f32_16x16x32_bf16(
                    aL[rf], bH[cf], acc[rf][cf], 0, 0, 0);
            }
    }

    float* g = Gp + (size_t)s * NN * HH;
    const int col0  = l & 15;
    const int rbase = (l >> 4) * 4;
#pragma unroll
    for (int rf = 0; rf < 2; ++rf)
#pragma unroll
        for (int cf = 0; cf < 4; ++cf)
#pragma unroll
            for (int r = 0; r < 4; ++r)
                g[(size_t)((rb0 + rf) * 16 + rbase + r) * HH + cf * 16 + col0]
                    = acc[rf][cf][r];
}

// ---------------------------------------------------------------------------
// Post: z = (wiu_in?) + (reduce_s Gsrc) @ W^T ; h = tanh(z)
//   nsplit==0: Gsrc is x [4096][64] directly (computes wiu), else Gp [8][..]
// Writes hf32 always; Bpack hi/lo (fragment layout) always; optional out2.
// grid 128 x 32 rows, 256 threads. Thread (iw,j) owns rows iw*8..+7 col j,
// which is exactly pack-lane l=(iw<<4)|(j&15), cf=j>>4 -> local pack, no LDS.
// ---------------------------------------------------------------------------
__global__ __launch_bounds__(256) void gesn_post(
    const float* __restrict__ Gsrc, int nsplit,
    const float* __restrict__ wiu_in, float* __restrict__ wiu_out,
    const float* __restrict__ W,                  // [64][64]
    float* __restrict__ hf32,
    short* __restrict__ Bhi, short* __restrict__ Blo,
    float* __restrict__ out2, int outc0)
{
    __shared__ float G_lds[32 * 68];
    __shared__ float W_lds[64 * 65];
    const int t = threadIdx.x;

    {   // W load (padded 65 -> conflict-free reads)
        const int j  = t >> 2;
        const int k0 = (t & 3) << 4;
#pragma unroll
        for (int q = 0; q < 16; ++q)
            W_lds[j * 65 + k0 + q] = W[j * 64 + k0 + q];
    }
    const int r0 = blockIdx.x * 32;

    // load(+reduce) G: 32x64 f32, 2 float4/thread
#pragma unroll
    for (int q = 0; q < 2; ++q) {
        const int f4  = t + q * 256;           // 0..511
        const int row = f4 >> 4;
        const int c   = (f4 & 15) * 4;
        float4 sum;
        if (nsplit == 0) {
            sum = *reinterpret_cast<const float4*>(
                Gsrc + (size_t)(r0 + row) * HH + c);
        } else {
            sum = make_float4(0.f, 0.f, 0.f, 0.f);
            for (int sidx = 0; sidx < nsplit; ++sidx) {
                const float4 v = *reinterpret_cast<const float4*>(
                    Gsrc + (size_t)sidx * NN * HH + (size_t)(r0 + row) * HH + c);
                sum.x += v.x; sum.y += v.y; sum.z += v.z; sum.w += v.w;
            }
        }
        *reinterpret_cast<float4*>(&G_lds[row * 68 + c]) = sum;
    }
    __syncthreads();

    const int j  = t & 63;
    const int iw = t >> 6;
    short hi8[8], lo8[8];
#pragma unroll
    for (int rr = 0; rr < 8; ++rr) {
        const int i = iw * 8 + rr;            // 0..31
        float z = wiu_in ? wiu_in[(size_t)(r0 + i) * HH + j] : 0.f;
#pragma unroll
        for (int m = 0; m < 64; ++m)
            z = fmaf(G_lds[i * 68 + m], W_lds[j * 65 + m], z);
        if (wiu_out) wiu_out[(size_t)(r0 + i) * HH + j] = z;
        const float hv = tanhf(z);
        hf32[(size_t)(r0 + i) * HH + j] = hv;
        if (out2) out2[(size_t)(r0 + i) * 128 + outc0 + j] = hv;
        __hip_bfloat16 bh = __float2bfloat16(hv);
        const float vh = __bfloat162float(bh);
        __hip_bfloat16 bl = __float2bfloat16(hv - vh);
        hi8[rr] = (short)bf16_bits(bh);
        lo8[rr] = (short)bf16_bits(bl);
    }
    // pack store: kb = r0>>5, cf = j>>4, lane = iw*16 + (j&15)
    const size_t off = ((size_t)((r0 >> 5) * 4 + (j >> 4)) * 64
                        + (iw * 16 + (j & 15))) * 8;
    *reinterpret_cast<bf16x8*>(Bhi + off) = *reinterpret_cast<bf16x8*>(hi8);
    *reinterpret_cast<bf16x8*>(Blo + off) = *reinterpret_cast<bf16x8*>(lo8);
}

// ---------------------------------------------------------------------------
// Fallback f32 path (round-0 kernels, kept for small-ws safety)
// ---------------------------------------------------------------------------
__global__ __launch_bounds__(256) void gesn_input_kernel(
    const float* __restrict__ x, const float* __restrict__ W,
    float* __restrict__ wiu, float* __restrict__ h)
{
    __shared__ float W_lds[64 * 65];
    __shared__ float x_lds[256];
    const int t = threadIdx.x;
    {
        const int j  = t >> 2;
        const int k0 = (t & 3) << 4;
#pragma unroll
        for (int q = 0; q < 16; ++q)
            W_lds[j * 65 + k0 + q] = W[j * 64 + k0 + q];
    }
    const int i0 = blockIdx.x * 4;
    x_lds[t] = x[i0 * 64 + t];
    __syncthreads();
    const int j = t & 63, i = t >> 6;
    float z = 0.f;
#pragma unroll
    for (int k = 0; k < 64; ++k)
        z = fmaf(x_lds[i * 64 + k], W_lds[j * 65 + k], z);
    const int gidx = (i0 + i) * 64 + j;
    wiu[gidx] = z;
    h[gidx]   = tanhf(z);
}

__global__ __launch_bounds__(256) void gesn_iter_kernel(
    const float* __restrict__ L, const float* __restrict__ h_in,
    const float* __restrict__ wiu, const float* __restrict__ W,
    float* __restrict__ h_out, float* __restrict__ out2, int out_col0)
{
    __shared__ float h_lds[64 * 64];
    __shared__ float L_lds[16 * 68];
    __shared__ float G_lds[16 * 68];
    __shared__ float W_lds[64 * 65];
    const int t = threadIdx.x;
    {
        const int j  = t >> 2;
        const int k0 = (t & 3) << 4;
#pragma unroll
        for (int q = 0; q < 16; ++q)
            W_lds[j * 65 + k0 + q] = W[j * 64 + k0 + q];
    }
    const int r0 = blockIdx.x * 16;
    const int p  = t >> 5;
    const int c0 = (t & 31) * 2;
    float acc00 = 0.f, acc01 = 0.f, acc10 = 0.f, acc11 = 0.f;
    const int lr = t >> 4;
    const int lc = (t & 15) * 4;
    for (int kb = 0; kb < 64; ++kb) {
        __syncthreads();
        const float4 lv = *reinterpret_cast<const float4*>(
            &L[(size_t)(r0 + lr) * 4096 + kb * 64 + lc]);
        *reinterpret_cast<float4*>(&L_lds[lr * 68 + lc]) = lv;
        const float4* hsrc = reinterpret_cast<const float4*>(h_in + kb * 4096);
        float4* hdst = reinterpret_cast<float4*>(h_lds);
#pragma unroll
        for (int q = 0; q < 4; ++q)
            hdst[t + 256 * q] = hsrc[t + 256 * q];
        __syncthreads();
#pragma unroll
        for (int kk = 0; kk < 64; ++kk) {
            const float  lv0 = L_lds[(2 * p) * 68 + kk];
            const float  lv1 = L_lds[(2 * p + 1) * 68 + kk];
            const float2 hv  = *reinterpret_cast<const float2*>(&h_lds[kk * 64 + c0]);
            acc00 = fmaf(lv0, hv.x, acc00);
            acc01 = fmaf(lv0, hv.y, acc01);
            acc10 = fmaf(lv1, hv.x, acc10);
            acc11 = fmaf(lv1, hv.y, acc11);
        }
    }
    G_lds[(2 * p) * 68 + c0]         = acc00;
    G_lds[(2 * p) * 68 + c0 + 1]     = acc01;
    G_lds[(2 * p + 1) * 68 + c0]     = acc10;
    G_lds[(2 * p + 1) * 68 + c0 + 1] = acc11;
    __syncthreads();
    const int j  = t & 63;
    const int iw = t >> 6;
#pragma unroll
    for (int rr = 0; rr < 4; ++rr) {
        const int i = iw * 4 + rr;
        float z = wiu[(size_t)(r0 + i) * 64 + j];
#pragma unroll
        for (int m = 0; m < 64; ++m)
            z = fmaf(G_lds[i * 68 + m], W_lds[j * 65 + m], z);
        const float hv = tanhf(z);
        h_out[(size_t)(r0 + i) * 64 + j] = hv;
        if (out2) out2[(size_t)(r0 + i) * 128 + out_col0 + j] = hv;
    }
}

// ---------------------------------------------------------------------------
extern "C" void kernel_launch(void* const* d_in, const int* in_sizes, int n_in,
                              void* d_out, int out_size, void* d_ws, size_t ws_size,
                              hipStream_t stream) {
    const float* X    = (const float*)d_in[0];
    const float* L    = (const float*)d_in[1];
    const float* Wih0 = (const float*)d_in[2];
    const float* Whh0 = (const float*)d_in[3];
    const float* Wih1 = (const float*)d_in[4];
    const float* Whh1 = (const float*)d_in[5];
    float* out = (float*)d_out;
    char* ws = (char*)d_ws;

    const size_t MB = 1024 * 1024;
    const size_t need = 76 * MB;

    if (ws_size >= need) {
        short* Ahi = (short*)(ws);                 // 32 MB
        short* Alo = (short*)(ws + 32 * MB);       // 32 MB
        short* Bhi = (short*)(ws + 64 * MB);       // 0.5 MB
        short* Blo = (short*)(ws + 64 * MB + 512 * 1024);
        float* wiu = (float*)(ws + 65 * MB);       // 1 MB
        float* hA  = (float*)(ws + 66 * MB);       // 1 MB
        float* hB  = (float*)(ws + 67 * MB);       // 1 MB
        float* Gp  = (float*)(ws + 68 * MB);       // 8 MB

        convert_L<<<8192, 256, 0, stream>>>(L, Ahi, Alo);

        for (int layer = 0; layer < 2; ++layer) {
            const float* x   = layer ? hA : X;
            const float* Wih = layer ? Wih1 : Wih0;
            const float* Whh = layer ? Whh1 : Whh0;
            float* hcur = layer ? hB : hA;

            // iter 1: wiu = x@Wih^T; h = tanh(wiu); pack h
            gesn_post<<<128, 256, 0, stream>>>(x, 0, nullptr, wiu, Wih,
                                               hcur, Bhi, Blo, nullptr, 0);
            // iters 2..10
            for (int it = 0; it < 9; ++it) {
                gesn_mm<<<256, 256, 0, stream>>>(Ahi, Alo, Bhi, Blo, Gp);
                float* o2 = (it == 8) ? out : nullptr;
                gesn_post<<<128, 256, 0, stream>>>(Gp, 8, wiu, nullptr, Whh,
                                                   hcur, Bhi, Blo, o2, layer * 64);
            }
        }
    } else {
        // f32 fallback (verified round-0 path)
        float* wiu = (float*)(ws);
        float* hA  = (float*)(ws + (1u << 20));
        float* hB  = (float*)(ws + (2u << 20));
        for (int layer = 0; layer < 2; ++layer) {
            const float* x   = layer ? hB : X;
            const float* Wih = layer ? Wih1 : Wih0;
            const float* Whh = layer ? Whh1 : Whh0;
            gesn_input_kernel<<<1024, 256, 0, stream>>>(x, Wih, wiu, hA);
            float* cur = hA;
            float* nxt = hB;
            for (int it = 0; it < 9; ++it) {
                float* o2 = (it == 8) ? out : nullptr;
                gesn_iter_kernel<<<256, 256, 0, stream>>>(L, cur, wiu, Whh, nxt,
                                                          o2, layer * 64);
                float* tmp = cur; cur = nxt; nxt = tmp;
            }
        }
    }
}

// Round 3
// 529.728 us; speedup vs baseline: 3.3107x; 1.2318x over previous
//
#include <hip/hip_runtime.h>
#include <hip/hip_bf16.h>
#include <math.h>

// DeepGESN: 2 layers of h = tanh(wiu + L @ (h @ W_hh^T)), 10 iters each.
// Rewrite: L@(h@W) == (L@h)@W. G=L@h in bf16 MFMA with two-term split
// (L=Lhi+Llo, h=hhi+hlo, 3 products -> ~2^-17 operand error; measured
// absmax 0.0098 vs 0.02 threshold). 64x64 projection + tanh in post.
//
// R2 changes: mm stages its B-slice (128KB) in LDS once (4x less B global
// traffic), 4-deep A prefetch to cover L3 latency at 1 wave/SIMD, post on
// 256 blocks (was 128).
//
// Pack layouts (lane-linear dwordx4 fragment loads):
//  Apack[rb][kb][l][8]: val = L[rb*16 + (l&15)][kb*32 + 8*(l>>4) + j]
//  Bpack[kb][cf][l][8]: val = h[kb*32 + 8*(l>>4) + j][cf*16 + (l&15)]
// mfma_f32_16x16x32_bf16: D[(l>>4)*4+r][l&15] (m89/m91 layout).

#define NN 4096
#define HH 64

typedef float  f32x4  __attribute__((ext_vector_type(4)));
typedef short  bf16x8 __attribute__((ext_vector_type(8)));

static __device__ __forceinline__ unsigned short bf16_bits(__hip_bfloat16 b) {
    union { __hip_bfloat16 b; unsigned short u; } cv; cv.b = b; return cv.u;
}

// ---------------------------------------------------------------------------
// Split + pack L -> Ahi/Alo (bf16 fragment-linear, 32MB each)
// grid 8192: rb = bid>>5 (256), kg = bid&31 (128-k group)
// ---------------------------------------------------------------------------
__global__ __launch_bounds__(256) void convert_L(
    const float* __restrict__ L, short* __restrict__ Ahi, short* __restrict__ Alo)
{
    __shared__ float T[16 * 132];
    const int t  = threadIdx.x;
    const int rb = blockIdx.x >> 5;
    const int kg = blockIdx.x & 31;

    {
        const int row = t >> 4;
        const int c4  = (t & 15) * 4;
        const float* src = L + (size_t)(rb * 16 + row) * NN + kg * 128;
        float4 v0 = *reinterpret_cast<const float4*>(src + c4);
        float4 v1 = *reinterpret_cast<const float4*>(src + c4 + 64);
        *reinterpret_cast<float4*>(&T[row * 132 + c4])      = v0;
        *reinterpret_cast<float4*>(&T[row * 132 + c4 + 64]) = v1;
    }
    __syncthreads();

    const int kbl = t >> 6;
    const int l   = t & 63;
    const int r   = l & 15, g = l >> 4;
    short hi8[8], lo8[8];
#pragma unroll
    for (int j = 0; j < 8; ++j) {
        const float v = T[r * 132 + kbl * 32 + g * 8 + j];
        __hip_bfloat16 bh = __float2bfloat16(v);
        const float vh = __bfloat162float(bh);
        __hip_bfloat16 bl = __float2bfloat16(v - vh);
        hi8[j] = (short)bf16_bits(bh);
        lo8[j] = (short)bf16_bits(bl);
    }
    const size_t off = ((size_t)(rb * 128 + kg * 4 + kbl) * 64 + l) * 8;
    *reinterpret_cast<bf16x8*>(Ahi + off) = *reinterpret_cast<bf16x8*>(hi8);
    *reinterpret_cast<bf16x8*>(Alo + off) = *reinterpret_cast<bf16x8*>(lo8);
}

// ---------------------------------------------------------------------------
// MFMA matmul: Gp[s] = partial (L @ h) over K-split s (K=512).
// grid 256 = 32 row-panels (128 rows) x 8 K-splits; 256 thr, 4 waves,
// wave w owns rowblocks {p*8+2w, +1}. B-slice staged ONCE in LDS (128KB).
// A: 4-deep prefetch from global (L3-resident stream).
// ---------------------------------------------------------------------------
__global__ __launch_bounds__(256) void gesn_mm(
    const short* __restrict__ Ahi, const short* __restrict__ Alo,
    const short* __restrict__ Bhi, const short* __restrict__ Blo,
    float* __restrict__ Gp)            // [8][4096][64]
{
    __shared__ short Bh_lds[16 * 4 * 64 * 8];   // 64KB  [kbl][cf][l][8]
    __shared__ short Bl_lds[16 * 4 * 64 * 8];   // 64KB

    const int t = threadIdx.x;
    const int w = t >> 6, l = t & 63;
    const int p = blockIdx.x >> 3;
    const int s = blockIdx.x & 7;
    const int rb0 = p * 8 + w * 2;
    const int kb0 = s * 16;

    // stage B-slice (contiguous 64KB per array), 16 dwordx4 per thread each
    {
        const short* srcH = Bhi + (size_t)kb0 * 4 * 64 * 8;
        const short* srcL = Blo + (size_t)kb0 * 4 * 64 * 8;
#pragma unroll
        for (int q = 0; q < 16; ++q) {
            const int idx = (q * 256 + t) * 8;
            *reinterpret_cast<bf16x8*>(&Bh_lds[idx]) =
                *reinterpret_cast<const bf16x8*>(srcH + idx);
            *reinterpret_cast<bf16x8*>(&Bl_lds[idx]) =
                *reinterpret_cast<const bf16x8*>(srcL + idx);
        }
    }
    __syncthreads();

    // A fragment offset for rowblock rb0+rf, k-block kb0+kbl
    const size_t abase0 = ((size_t)((rb0 + 0) * 128 + kb0) * 64 + l) * 8;
    const size_t abase1 = ((size_t)((rb0 + 1) * 128 + kb0) * 64 + l) * 8;

    bf16x8 aH[4][2], aL[4][2];     // 4-deep prefetch ring (static idx via unroll)
#pragma unroll
    for (int q = 0; q < 3; ++q) {
        aH[q][0] = *reinterpret_cast<const bf16x8*>(Ahi + abase0 + (size_t)q * 512);
        aL[q][0] = *reinterpret_cast<const bf16x8*>(Alo + abase0 + (size_t)q * 512);
        aH[q][1] = *reinterpret_cast<const bf16x8*>(Ahi + abase1 + (size_t)q * 512);
        aL[q][1] = *reinterpret_cast<const bf16x8*>(Alo + abase1 + (size_t)q * 512);
    }

    f32x4 acc[2][4] = {};

#pragma unroll
    for (int kbl = 0; kbl < 16; ++kbl) {
        const int cur = kbl & 3;
        if (kbl + 3 < 16) {
            const int nxt = (kbl + 3) & 3;
            aH[nxt][0] = *reinterpret_cast<const bf16x8*>(Ahi + abase0 + (size_t)(kbl + 3) * 512);
            aL[nxt][0] = *reinterpret_cast<const bf16x8*>(Alo + abase0 + (size_t)(kbl + 3) * 512);
            aH[nxt][1] = *reinterpret_cast<const bf16x8*>(Ahi + abase1 + (size_t)(kbl + 3) * 512);
            aL[nxt][1] = *reinterpret_cast<const bf16x8*>(Alo + abase1 + (size_t)(kbl + 3) * 512);
        }
        bf16x8 bH[4], bL[4];
#pragma unroll
        for (int cf = 0; cf < 4; ++cf) {
            const int idx = ((kbl * 4 + cf) * 64 + l) * 8;
            bH[cf] = *reinterpret_cast<const bf16x8*>(&Bh_lds[idx]);
            bL[cf] = *reinterpret_cast<const bf16x8*>(&Bl_lds[idx]);
        }
#pragma unroll
        for (int rf = 0; rf < 2; ++rf)
#pragma unroll
            for (int cf = 0; cf < 4; ++cf) {
                acc[rf][cf] = __builtin_amdgcn_mfma_f32_16x16x32_bf16(
                    aH[cur][rf], bH[cf], acc[rf][cf], 0, 0, 0);
                acc[rf][cf] = __builtin_amdgcn_mfma_f32_16x16x32_bf16(
                    aH[cur][rf], bL[cf], acc[rf][cf], 0, 0, 0);
                acc[rf][cf] = __builtin_amdgcn_mfma_f32_16x16x32_bf16(
                    aL[cur][rf], bH[cf], acc[rf][cf], 0, 0, 0);
            }
    }

    float* g = Gp + (size_t)s * NN * HH;
    const int col0  = l & 15;
    const int rbase = (l >> 4) * 4;
#pragma unroll
    for (int rf = 0; rf < 2; ++rf)
#pragma unroll
        for (int cf = 0; cf < 4; ++cf)
#pragma unroll
            for (int r = 0; r < 4; ++r)
                g[(size_t)((rb0 + rf) * 16 + rbase + r) * HH + cf * 16 + col0]
                    = acc[rf][cf][r];
}

// ---------------------------------------------------------------------------
// Post: z = (wiu_in?) + (reduce_s Gsrc) @ W^T ; h = tanh(z)
//   nsplit==0: Gsrc is x [4096][64] (computes wiu), else Gp [8][4096][64].
// grid 256 x 16 rows, 256 threads. bf16 pack goes through a small LDS tile
// so 128 threads can emit bf16x8 fragment stores (8 consecutive rows each).
// ---------------------------------------------------------------------------
__global__ __launch_bounds__(256) void gesn_post(
    const float* __restrict__ Gsrc, int nsplit,
    const float* __restrict__ wiu_in, float* __restrict__ wiu_out,
    const float* __restrict__ W,                  // [64][64]
    float* __restrict__ hf32,
    short* __restrict__ Bhi, short* __restrict__ Blo,
    float* __restrict__ out2, int outc0)
{
    __shared__ float W_lds[64 * 65];
    __shared__ float G_lds[16 * 68];
    __shared__ unsigned short Hi_lds[16][66];
    __shared__ unsigned short Lo_lds[16][66];
    const int t = threadIdx.x;

    {   // W load
        const int j  = t >> 2;
        const int k0 = (t & 3) << 4;
#pragma unroll
        for (int q = 0; q < 16; ++q)
            W_lds[j * 65 + k0 + q] = W[j * 64 + k0 + q];
    }
    const int r0 = blockIdx.x * 16;

    // load(+reduce) G: 16x64 f32 = 256 float4, one per thread
    {
        const int row = t >> 4;
        const int c4  = (t & 15) * 4;
        float4 sum;
        if (nsplit == 0) {
            sum = *reinterpret_cast<const float4*>(
                Gsrc + (size_t)(r0 + row) * HH + c4);
        } else {
            sum = make_float4(0.f, 0.f, 0.f, 0.f);
            for (int sidx = 0; sidx < nsplit; ++sidx) {
                const float4 v = *reinterpret_cast<const float4*>(
                    Gsrc + (size_t)sidx * NN * HH + (size_t)(r0 + row) * HH + c4);
                sum.x += v.x; sum.y += v.y; sum.z += v.z; sum.w += v.w;
            }
        }
        *reinterpret_cast<float4*>(&G_lds[row * 68 + c4]) = sum;
    }
    __syncthreads();

    const int j  = t & 63;
    const int ig = t >> 6;
#pragma unroll
    for (int rr = 0; rr < 4; ++rr) {
        const int i = ig * 4 + rr;            // 0..15
        float z = wiu_in ? wiu_in[(size_t)(r0 + i) * HH + j] : 0.f;
#pragma unroll
        for (int m = 0; m < 64; ++m)
            z = fmaf(G_lds[i * 68 + m], W_lds[j * 65 + m], z);
        if (wiu_out) wiu_out[(size_t)(r0 + i) * HH + j] = z;
        const float hv = tanhf(z);
        hf32[(size_t)(r0 + i) * HH + j] = hv;
        if (out2) out2[(size_t)(r0 + i) * 128 + outc0 + j] = hv;
        __hip_bfloat16 bh = __float2bfloat16(hv);
        const float vh = __bfloat162float(bh);
        __hip_bfloat16 bl = __float2bfloat16(hv - vh);
        Hi_lds[i][j] = bf16_bits(bh);
        Lo_lds[i][j] = bf16_bits(bl);
    }
    __syncthreads();

    // pack: 128 threads, each owns 8 consecutive rows at one column
    if (t < 128) {
        const int j2     = t & 63;
        const int glocal = t >> 6;                 // 0..1 (8-row group in block)
        const int kb     = r0 >> 5;
        const int gg     = ((r0 & 31) >> 3) + glocal;  // 8-row group in 32-row kb
        const int cf     = j2 >> 4;
        const int lane   = gg * 16 + (j2 & 15);
        short hi8[8], lo8[8];
#pragma unroll
        for (int jj = 0; jj < 8; ++jj) {
            const int i = glocal * 8 + jj;
            hi8[jj] = (short)Hi_lds[i][j2];
            lo8[jj] = (short)Lo_lds[i][j2];
        }
        const size_t off = ((size_t)(kb * 4 + cf) * 64 + lane) * 8;
        *reinterpret_cast<bf16x8*>(Bhi + off) = *reinterpret_cast<bf16x8*>(hi8);
        *reinterpret_cast<bf16x8*>(Blo + off) = *reinterpret_cast<bf16x8*>(lo8);
    }
}

// ---------------------------------------------------------------------------
// Fallback f32 path (round-0 kernels, small-ws safety)
// ---------------------------------------------------------------------------
__global__ __launch_bounds__(256) void gesn_input_kernel(
    const float* __restrict__ x, const float* __restrict__ W,
    float* __restrict__ wiu, float* __restrict__ h)
{
    __shared__ float W_lds[64 * 65];
    __shared__ float x_lds[256];
    const int t = threadIdx.x;
    {
        const int j  = t >> 2;
        const int k0 = (t & 3) << 4;
#pragma unroll
        for (int q = 0; q < 16; ++q)
            W_lds[j * 65 + k0 + q] = W[j * 64 + k0 + q];
    }
    const int i0 = blockIdx.x * 4;
    x_lds[t] = x[i0 * 64 + t];
    __syncthreads();
    const int j = t & 63, i = t >> 6;
    float z = 0.f;
#pragma unroll
    for (int k = 0; k < 64; ++k)
        z = fmaf(x_lds[i * 64 + k], W_lds[j * 65 + k], z);
    const int gidx = (i0 + i) * 64 + j;
    wiu[gidx] = z;
    h[gidx]   = tanhf(z);
}

__global__ __launch_bounds__(256) void gesn_iter_kernel(
    const float* __restrict__ L, const float* __restrict__ h_in,
    const float* __restrict__ wiu, const float* __restrict__ W,
    float* __restrict__ h_out, float* __restrict__ out2, int out_col0)
{
    __shared__ float h_lds[64 * 64];
    __shared__ float L_lds[16 * 68];
    __shared__ float G_lds[16 * 68];
    __shared__ float W_lds[64 * 65];
    const int t = threadIdx.x;
    {
        const int j  = t >> 2;
        const int k0 = (t & 3) << 4;
#pragma unroll
        for (int q = 0; q < 16; ++q)
            W_lds[j * 65 + k0 + q] = W[j * 64 + k0 + q];
    }
    const int r0 = blockIdx.x * 16;
    const int p  = t >> 5;
    const int c0 = (t & 31) * 2;
    float acc00 = 0.f, acc01 = 0.f, acc10 = 0.f, acc11 = 0.f;
    const int lr = t >> 4;
    const int lc = (t & 15) * 4;
    for (int kb = 0; kb < 64; ++kb) {
        __syncthreads();
        const float4 lv = *reinterpret_cast<const float4*>(
            &L[(size_t)(r0 + lr) * 4096 + kb * 64 + lc]);
        *reinterpret_cast<float4*>(&L_lds[lr * 68 + lc]) = lv;
        const float4* hsrc = reinterpret_cast<const float4*>(h_in + kb * 4096);
        float4* hdst = reinterpret_cast<float4*>(h_lds);
#pragma unroll
        for (int q = 0; q < 4; ++q)
            hdst[t + 256 * q] = hsrc[t + 256 * q];
        __syncthreads();
#pragma unroll
        for (int kk = 0; kk < 64; ++kk) {
            const float  lv0 = L_lds[(2 * p) * 68 + kk];
            const float  lv1 = L_lds[(2 * p + 1) * 68 + kk];
            const float2 hv  = *reinterpret_cast<const float2*>(&h_lds[kk * 64 + c0]);
            acc00 = fmaf(lv0, hv.x, acc00);
            acc01 = fmaf(lv0, hv.y, acc01);
            acc10 = fmaf(lv1, hv.x, acc10);
            acc11 = fmaf(lv1, hv.y, acc11);
        }
    }
    G_lds[(2 * p) * 68 + c0]         = acc00;
    G_lds[(2 * p) * 68 + c0 + 1]     = acc01;
    G_lds[(2 * p + 1) * 68 + c0]     = acc10;
    G_lds[(2 * p + 1) * 68 + c0 + 1] = acc11;
    __syncthreads();
    const int j  = t & 63;
    const int iw = t >> 6;
#pragma unroll
    for (int rr = 0; rr < 4; ++rr) {
        const int i = iw * 4 + rr;
        float z = wiu[(size_t)(r0 + i) * 64 + j];
#pragma unroll
        for (int m = 0; m < 64; ++m)
            z = fmaf(G_lds[i * 68 + m], W_lds[j * 65 + m], z);
        const float hv = tanhf(z);
        h_out[(size_t)(r0 + i) * 64 + j] = hv;
        if (out2) out2[(size_t)(r0 + i) * 128 + out_col0 + j] = hv;
    }
}

// ---------------------------------------------------------------------------
extern "C" void kernel_launch(void* const* d_in, const int* in_sizes, int n_in,
                              void* d_out, int out_size, void* d_ws, size_t ws_size,
                              hipStream_t stream) {
    const float* X    = (const float*)d_in[0];
    const float* L    = (const float*)d_in[1];
    const float* Wih0 = (const float*)d_in[2];
    const float* Whh0 = (const float*)d_in[3];
    const float* Wih1 = (const float*)d_in[4];
    const float* Whh1 = (const float*)d_in[5];
    float* out = (float*)d_out;
    char* ws = (char*)d_ws;

    const size_t MB = 1024 * 1024;
    const size_t need = 76 * MB;

    if (ws_size >= need) {
        short* Ahi = (short*)(ws);                 // 32 MB
        short* Alo = (short*)(ws + 32 * MB);       // 32 MB
        short* Bhi = (short*)(ws + 64 * MB);       // 0.5 MB
        short* Blo = (short*)(ws + 64 * MB + 512 * 1024);
        float* wiu = (float*)(ws + 65 * MB);       // 1 MB
        float* hA  = (float*)(ws + 66 * MB);       // 1 MB
        float* hB  = (float*)(ws + 67 * MB);       // 1 MB
        float* Gp  = (float*)(ws + 68 * MB);       // 8 MB

        convert_L<<<8192, 256, 0, stream>>>(L, Ahi, Alo);

        for (int layer = 0; layer < 2; ++layer) {
            const float* x   = layer ? hA : X;
            const float* Wih = layer ? Wih1 : Wih0;
            const float* Whh = layer ? Whh1 : Whh0;
            float* hcur = layer ? hB : hA;

            // iter 1: wiu = x@Wih^T; h = tanh(wiu); pack h
            gesn_post<<<256, 256, 0, stream>>>(x, 0, nullptr, wiu, Wih,
                                               hcur, Bhi, Blo, nullptr, 0);
            // iters 2..10
            for (int it = 0; it < 9; ++it) {
                gesn_mm<<<256, 256, 0, stream>>>(Ahi, Alo, Bhi, Blo, Gp);
                float* o2 = (it == 8) ? out : nullptr;
                gesn_post<<<256, 256, 0, stream>>>(Gp, 8, wiu, nullptr, Whh,
                                                   hcur, Bhi, Blo, o2, layer * 64);
            }
        }
    } else {
        // f32 fallback (verified round-0 path)
        float* wiu = (float*)(ws);
        float* hA  = (float*)(ws + (1u << 20));
        float* hB  = (float*)(ws + (2u << 20));
        for (int layer = 0; layer < 2; ++layer) {
            const float* x   = layer ? hB : X;
            const float* Wih = layer ? Wih1 : Wih0;
            const float* Whh = layer ? Whh1 : Whh0;
            gesn_input_kernel<<<1024, 256, 0, stream>>>(x, Wih, wiu, hA);
            float* cur = hA;
            float* nxt = hB;
            for (int it = 0; it < 9; ++it) {
                float* o2 = (it == 8) ? out : nullptr;
                gesn_iter_kernel<<<256, 256, 0, stream>>>(L, cur, wiu, Whh, nxt,
                                                          o2, layer * 64);
                float* tmp = cur; cur = nxt; nxt = tmp;
            }
        }
    }
}

// Round 5
// 516.758 us; speedup vs baseline: 3.3938x; 1.0251x over previous
//
#include <hip/hip_runtime.h>
#include <hip/hip_bf16.h>
#include <math.h>

// DeepGESN: 2 layers of h = tanh(wiu + L @ (h @ W_hh^T)), 10 iters each.
// Rewrite: L@(h@W) == (L@h)@W. G=L@h in bf16 MFMA with two-term split
// (L=Lhi+Llo, h=hhi+hlo, 3 products; measured absmax 0.0098 vs 0.02 thr).
// 64x64 projection + tanh in post.
//
// R3 changes (unmeasured in R4 due to broker timeout; resubmitted verbatim):
// mm at 512 threads (2 waves/SIMD, was 1 -- latency hiding via TLP),
// accumulator split into two independent MFMA chains per (cf).
//
// Pack layouts (lane-linear dwordx4 fragment loads):
//  Apack[rb][kb][l][8]: val = L[rb*16 + (l&15)][kb*32 + 8*(l>>4) + j]
//  Bpack[kb][cf][l][8]: val = h[kb*32 + 8*(l>>4) + j][cf*16 + (l&15)]
// mfma_f32_16x16x32_bf16: D[(l>>4)*4+r][l&15] (m89/m91 layout).

#define NN 4096
#define HH 64

typedef float  f32x4  __attribute__((ext_vector_type(4)));
typedef short  bf16x8 __attribute__((ext_vector_type(8)));

static __device__ __forceinline__ unsigned short bf16_bits(__hip_bfloat16 b) {
    union { __hip_bfloat16 b; unsigned short u; } cv; cv.b = b; return cv.u;
}

// ---------------------------------------------------------------------------
// Split + pack L -> Ahi/Alo (bf16 fragment-linear, 32MB each)
// grid 8192: rb = bid>>5 (256), kg = bid&31 (128-k group)
// ---------------------------------------------------------------------------
__global__ __launch_bounds__(256) void convert_L(
    const float* __restrict__ L, short* __restrict__ Ahi, short* __restrict__ Alo)
{
    __shared__ float T[16 * 132];
    const int t  = threadIdx.x;
    const int rb = blockIdx.x >> 5;
    const int kg = blockIdx.x & 31;

    {
        const int row = t >> 4;
        const int c4  = (t & 15) * 4;
        const float* src = L + (size_t)(rb * 16 + row) * NN + kg * 128;
        float4 v0 = *reinterpret_cast<const float4*>(src + c4);
        float4 v1 = *reinterpret_cast<const float4*>(src + c4 + 64);
        *reinterpret_cast<float4*>(&T[row * 132 + c4])      = v0;
        *reinterpret_cast<float4*>(&T[row * 132 + c4 + 64]) = v1;
    }
    __syncthreads();

    const int kbl = t >> 6;
    const int l   = t & 63;
    const int r   = l & 15, g = l >> 4;
    short hi8[8], lo8[8];
#pragma unroll
    for (int j = 0; j < 8; ++j) {
        const float v = T[r * 132 + kbl * 32 + g * 8 + j];
        __hip_bfloat16 bh = __float2bfloat16(v);
        const float vh = __bfloat162float(bh);
        __hip_bfloat16 bl = __float2bfloat16(v - vh);
        hi8[j] = (short)bf16_bits(bh);
        lo8[j] = (short)bf16_bits(bl);
    }
    const size_t off = ((size_t)(rb * 128 + kg * 4 + kbl) * 64 + l) * 8;
    *reinterpret_cast<bf16x8*>(Ahi + off) = *reinterpret_cast<bf16x8*>(hi8);
    *reinterpret_cast<bf16x8*>(Alo + off) = *reinterpret_cast<bf16x8*>(lo8);
}

// ---------------------------------------------------------------------------
// MFMA matmul: Gp[s] = partial (L @ h) over K-split s (K=512).
// grid 256 = 32 row-panels (128 rows) x 8 K-splits; 512 thr = 8 waves
// (2 waves/SIMD), wave w owns rowblock p*8+w. B-slice staged once in LDS
// (128KB). A: 4-deep register prefetch (L3-resident stream). Two
// accumulator chains per cf (accP: hi*hi, accQ: hi*lo + lo*hi).
// ---------------------------------------------------------------------------
__global__ __launch_bounds__(512) void gesn_mm(
    const short* __restrict__ Ahi, const short* __restrict__ Alo,
    const short* __restrict__ Bhi, const short* __restrict__ Blo,
    float* __restrict__ Gp)            // [8][4096][64]
{
    __shared__ short Bh_lds[16 * 4 * 64 * 8];   // 64KB  [kbl][cf][l][8]
    __shared__ short Bl_lds[16 * 4 * 64 * 8];   // 64KB

    const int t = threadIdx.x;
    const int w = t >> 6, l = t & 63;
    const int p = blockIdx.x >> 3;
    const int s = blockIdx.x & 7;
    const int rb = p * 8 + w;          // this wave's 16-row block
    const int kb0 = s * 16;

    // stage B-slice: 4096 bf16x8 frags per array, 8 per thread each
    {
        const short* srcH = Bhi + (size_t)kb0 * 4 * 64 * 8;
        const short* srcL = Blo + (size_t)kb0 * 4 * 64 * 8;
#pragma unroll
        for (int q = 0; q < 8; ++q) {
            const int idx = (q * 512 + t) * 8;
            *reinterpret_cast<bf16x8*>(&Bh_lds[idx]) =
                *reinterpret_cast<const bf16x8*>(srcH + idx);
            *reinterpret_cast<bf16x8*>(&Bl_lds[idx]) =
                *reinterpret_cast<const bf16x8*>(srcL + idx);
        }
    }
    __syncthreads();

    const size_t abase = ((size_t)(rb * 128 + kb0) * 64 + l) * 8;

    bf16x8 aH[4], aL[4];               // prefetch ring (static idx via unroll)
#pragma unroll
    for (int q = 0; q < 3; ++q) {
        aH[q] = *reinterpret_cast<const bf16x8*>(Ahi + abase + (size_t)q * 512);
        aL[q] = *reinterpret_cast<const bf16x8*>(Alo + abase + (size_t)q * 512);
    }

    f32x4 accP[4] = {};                // aH*bH
    f32x4 accQ[4] = {};                // aH*bL + aL*bH

#pragma unroll
    for (int kbl = 0; kbl < 16; ++kbl) {
        const int cur = kbl & 3;
        if (kbl + 3 < 16) {
            const int nxt = (kbl + 3) & 3;
            aH[nxt] = *reinterpret_cast<const bf16x8*>(Ahi + abase + (size_t)(kbl + 3) * 512);
            aL[nxt] = *reinterpret_cast<const bf16x8*>(Alo + abase + (size_t)(kbl + 3) * 512);
        }
        bf16x8 bH[4], bL[4];
#pragma unroll
        for (int cf = 0; cf < 4; ++cf) {
            const int idx = ((kbl * 4 + cf) * 64 + l) * 8;
            bH[cf] = *reinterpret_cast<const bf16x8*>(&Bh_lds[idx]);
            bL[cf] = *reinterpret_cast<const bf16x8*>(&Bl_lds[idx]);
        }
#pragma unroll
        for (int cf = 0; cf < 4; ++cf) {
            accP[cf] = __builtin_amdgcn_mfma_f32_16x16x32_bf16(
                aH[cur], bH[cf], accP[cf], 0, 0, 0);
            accQ[cf] = __builtin_amdgcn_mfma_f32_16x16x32_bf16(
                aH[cur], bL[cf], accQ[cf], 0, 0, 0);
            accQ[cf] = __builtin_amdgcn_mfma_f32_16x16x32_bf16(
                aL[cur], bH[cf], accQ[cf], 0, 0, 0);
        }
    }

    float* g = Gp + (size_t)s * NN * HH;
    const int col0  = l & 15;
    const int rbase = (l >> 4) * 4;
#pragma unroll
    for (int cf = 0; cf < 4; ++cf)
#pragma unroll
        for (int r = 0; r < 4; ++r)
            g[(size_t)(rb * 16 + rbase + r) * HH + cf * 16 + col0]
                = accP[cf][r] + accQ[cf][r];
}

// ---------------------------------------------------------------------------
// Post: z = (wiu_in?) + (reduce_s Gsrc) @ W^T ; h = tanh(z)
//   nsplit==0: Gsrc is x [4096][64] (computes wiu), else Gp [8][4096][64].
// grid 256 x 16 rows, 256 threads. bf16 pack via small LDS transpose tile.
// ---------------------------------------------------------------------------
__global__ __launch_bounds__(256) void gesn_post(
    const float* __restrict__ Gsrc, int nsplit,
    const float* __restrict__ wiu_in, float* __restrict__ wiu_out,
    const float* __restrict__ W,                  // [64][64]
    float* __restrict__ hf32,
    short* __restrict__ Bhi, short* __restrict__ Blo,
    float* __restrict__ out2, int outc0)
{
    __shared__ float W_lds[64 * 65];
    __shared__ float G_lds[16 * 68];
    __shared__ unsigned short Hi_lds[16][66];
    __shared__ unsigned short Lo_lds[16][66];
    const int t = threadIdx.x;

    {   // W load
        const int j  = t >> 2;
        const int k0 = (t & 3) << 4;
#pragma unroll
        for (int q = 0; q < 16; ++q)
            W_lds[j * 65 + k0 + q] = W[j * 64 + k0 + q];
    }
    const int r0 = blockIdx.x * 16;

    // load(+reduce) G: 16x64 f32 = 256 float4, one per thread
    {
        const int row = t >> 4;
        const int c4  = (t & 15) * 4;
        float4 sum;
        if (nsplit == 0) {
            sum = *reinterpret_cast<const float4*>(
                Gsrc + (size_t)(r0 + row) * HH + c4);
        } else {
            sum = make_float4(0.f, 0.f, 0.f, 0.f);
            for (int sidx = 0; sidx < nsplit; ++sidx) {
                const float4 v = *reinterpret_cast<const float4*>(
                    Gsrc + (size_t)sidx * NN * HH + (size_t)(r0 + row) * HH + c4);
                sum.x += v.x; sum.y += v.y; sum.z += v.z; sum.w += v.w;
            }
        }
        *reinterpret_cast<float4*>(&G_lds[row * 68 + c4]) = sum;
    }
    __syncthreads();

    const int j  = t & 63;
    const int ig = t >> 6;
#pragma unroll
    for (int rr = 0; rr < 4; ++rr) {
        const int i = ig * 4 + rr;            // 0..15
        float z = wiu_in ? wiu_in[(size_t)(r0 + i) * HH + j] : 0.f;
#pragma unroll
        for (int m = 0; m < 64; ++m)
            z = fmaf(G_lds[i * 68 + m], W_lds[j * 65 + m], z);
        if (wiu_out) wiu_out[(size_t)(r0 + i) * HH + j] = z;
        const float hv = tanhf(z);
        hf32[(size_t)(r0 + i) * HH + j] = hv;
        if (out2) out2[(size_t)(r0 + i) * 128 + outc0 + j] = hv;
        __hip_bfloat16 bh = __float2bfloat16(hv);
        const float vh = __bfloat162float(bh);
        __hip_bfloat16 bl = __float2bfloat16(hv - vh);
        Hi_lds[i][j] = bf16_bits(bh);
        Lo_lds[i][j] = bf16_bits(bl);
    }
    __syncthreads();

    // pack: 128 threads, each owns 8 consecutive rows at one column
    if (t < 128) {
        const int j2     = t & 63;
        const int glocal = t >> 6;                 // 0..1
        const int kb     = r0 >> 5;
        const int gg     = ((r0 & 31) >> 3) + glocal;
        const int cf     = j2 >> 4;
        const int lane   = gg * 16 + (j2 & 15);
        short hi8[8], lo8[8];
#pragma unroll
        for (int jj = 0; jj < 8; ++jj) {
            const int i = glocal * 8 + jj;
            hi8[jj] = (short)Hi_lds[i][j2];
            lo8[jj] = (short)Lo_lds[i][j2];
        }
        const size_t off = ((size_t)(kb * 4 + cf) * 64 + lane) * 8;
        *reinterpret_cast<bf16x8*>(Bhi + off) = *reinterpret_cast<bf16x8*>(hi8);
        *reinterpret_cast<bf16x8*>(Blo + off) = *reinterpret_cast<bf16x8*>(lo8);
    }
}

// ---------------------------------------------------------------------------
// Fallback f32 path (round-0 kernels, small-ws safety)
// ---------------------------------------------------------------------------
__global__ __launch_bounds__(256) void gesn_input_kernel(
    const float* __restrict__ x, const float* __restrict__ W,
    float* __restrict__ wiu, float* __restrict__ h)
{
    __shared__ float W_lds[64 * 65];
    __shared__ float x_lds[256];
    const int t = threadIdx.x;
    {
        const int j  = t >> 2;
        const int k0 = (t & 3) << 4;
#pragma unroll
        for (int q = 0; q < 16; ++q)
            W_lds[j * 65 + k0 + q] = W[j * 64 + k0 + q];
    }
    const int i0 = blockIdx.x * 4;
    x_lds[t] = x[i0 * 64 + t];
    __syncthreads();
    const int j = t & 63, i = t >> 6;
    float z = 0.f;
#pragma unroll
    for (int k = 0; k < 64; ++k)
        z = fmaf(x_lds[i * 64 + k], W_lds[j * 65 + k], z);
    const int gidx = (i0 + i) * 64 + j;
    wiu[gidx] = z;
    h[gidx]   = tanhf(z);
}

__global__ __launch_bounds__(256) void gesn_iter_kernel(
    const float* __restrict__ L, const float* __restrict__ h_in,
    const float* __restrict__ wiu, const float* __restrict__ W,
    float* __restrict__ h_out, float* __restrict__ out2, int out_col0)
{
    __shared__ float h_lds[64 * 64];
    __shared__ float L_lds[16 * 68];
    __shared__ float G_lds[16 * 68];
    __shared__ float W_lds[64 * 65];
    const int t = threadIdx.x;
    {
        const int j  = t >> 2;
        const int k0 = (t & 3) << 4;
#pragma unroll
        for (int q = 0; q < 16; ++q)
            W_lds[j * 65 + k0 + q] = W[j * 64 + k0 + q];
    }
    const int r0 = blockIdx.x * 16;
    const int p  = t >> 5;
    const int c0 = (t & 31) * 2;
    float acc00 = 0.f, acc01 = 0.f, acc10 = 0.f, acc11 = 0.f;
    const int lr = t >> 4;
    const int lc = (t & 15) * 4;
    for (int kb = 0; kb < 64; ++kb) {
        __syncthreads();
        const float4 lv = *reinterpret_cast<const float4*>(
            &L[(size_t)(r0 + lr) * 4096 + kb * 64 + lc]);
        *reinterpret_cast<float4*>(&L_lds[lr * 68 + lc]) = lv;
        const float4* hsrc = reinterpret_cast<const float4*>(h_in + kb * 4096);
        float4* hdst = reinterpret_cast<float4*>(h_lds);
#pragma unroll
        for (int q = 0; q < 4; ++q)
            hdst[t + 256 * q] = hsrc[t + 256 * q];
        __syncthreads();
#pragma unroll
        for (int kk = 0; kk < 64; ++kk) {
            const float  lv0 = L_lds[(2 * p) * 68 + kk];
            const float  lv1 = L_lds[(2 * p + 1) * 68 + kk];
            const float2 hv  = *reinterpret_cast<const float2*>(&h_lds[kk * 64 + c0]);
            acc00 = fmaf(lv0, hv.x, acc00);
            acc01 = fmaf(lv0, hv.y, acc01);
            acc10 = fmaf(lv1, hv.x, acc10);
            acc11 = fmaf(lv1, hv.y, acc11);
        }
    }
    G_lds[(2 * p) * 68 + c0]         = acc00;
    G_lds[(2 * p) * 68 + c0 + 1]     = acc01;
    G_lds[(2 * p + 1) * 68 + c0]     = acc10;
    G_lds[(2 * p + 1) * 68 + c0 + 1] = acc11;
    __syncthreads();
    const int j  = t & 63;
    const int iw = t >> 6;
#pragma unroll
    for (int rr = 0; rr < 4; ++rr) {
        const int i = iw * 4 + rr;
        float z = wiu[(size_t)(r0 + i) * 64 + j];
#pragma unroll
        for (int m = 0; m < 64; ++m)
            z = fmaf(G_lds[i * 68 + m], W_lds[j * 65 + m], z);
        const float hv = tanhf(z);
        h_out[(size_t)(r0 + i) * 64 + j] = hv;
        if (out2) out2[(size_t)(r0 + i) * 128 + out_col0 + j] = hv;
    }
}

// ---------------------------------------------------------------------------
extern "C" void kernel_launch(void* const* d_in, const int* in_sizes, int n_in,
                              void* d_out, int out_size, void* d_ws, size_t ws_size,
                              hipStream_t stream) {
    const float* X    = (const float*)d_in[0];
    const float* L    = (const float*)d_in[1];
    const float* Wih0 = (const float*)d_in[2];
    const float* Whh0 = (const float*)d_in[3];
    const float* Wih1 = (const float*)d_in[4];
    const float* Whh1 = (const float*)d_in[5];
    float* out = (float*)d_out;
    char* ws = (char*)d_ws;

    const size_t MB = 1024 * 1024;
    const size_t need = 76 * MB;

    if (ws_size >= need) {
        short* Ahi = (short*)(ws);                 // 32 MB
        short* Alo = (short*)(ws + 32 * MB);       // 32 MB
        short* Bhi = (short*)(ws + 64 * MB);       // 0.5 MB
        short* Blo = (short*)(ws + 64 * MB + 512 * 1024);
        float* wiu = (float*)(ws + 65 * MB);       // 1 MB
        float* hA  = (float*)(ws + 66 * MB);       // 1 MB
        float* hB  = (float*)(ws + 67 * MB);       // 1 MB
        float* Gp  = (float*)(ws + 68 * MB);       // 8 MB

        convert_L<<<8192, 256, 0, stream>>>(L, Ahi, Alo);

        for (int layer = 0; layer < 2; ++layer) {
            const float* x   = layer ? hA : X;
            const float* Wih = layer ? Wih1 : Wih0;
            const float* Whh = layer ? Whh1 : Whh0;
            float* hcur = layer ? hB : hA;

            // iter 1: wiu = x@Wih^T; h = tanh(wiu); pack h
            gesn_post<<<256, 256, 0, stream>>>(x, 0, nullptr, wiu, Wih,
                                               hcur, Bhi, Blo, nullptr, 0);
            // iters 2..10
            for (int it = 0; it < 9; ++it) {
                gesn_mm<<<256, 512, 0, stream>>>(Ahi, Alo, Bhi, Blo, Gp);
                float* o2 = (it == 8) ? out : nullptr;
                gesn_post<<<256, 256, 0, stream>>>(Gp, 8, wiu, nullptr, Whh,
                                                   hcur, Bhi, Blo, o2, layer * 64);
            }
        }
    } else {
        // f32 fallback (verified round-0 path)
        float* wiu = (float*)(ws);
        float* hA  = (float*)(ws + (1u << 20));
        float* hB  = (float*)(ws + (2u << 20));
        for (int layer = 0; layer < 2; ++layer) {
            const float* x   = layer ? hB : X;
            const float* Wih = layer ? Wih1 : Wih0;
            const float* Whh = layer ? Whh1 : Whh0;
            gesn_input_kernel<<<1024, 256, 0, stream>>>(x, Wih, wiu, hA);
            float* cur = hA;
            float* nxt = hB;
            for (int it = 0; it < 9; ++it) {
                float* o2 = (it == 8) ? out : nullptr;
                gesn_iter_kernel<<<256, 256, 0, stream>>>(L, cur, wiu, Whh, nxt,
                                                          o2, layer * 64);
                float* tmp = cur; cur = nxt; nxt = tmp;
            }
        }
    }
}

// Round 6
// 509.390 us; speedup vs baseline: 3.4429x; 1.0145x over previous
//
#include <hip/hip_runtime.h>
#include <hip/hip_bf16.h>
#include <math.h>

// DeepGESN: 2 layers of h = tanh(wiu + L @ (h @ W_hh^T)), 10 iters each.
// Rewrite: L@(h@W) == (L@h)@W. G=L@h in bf16 MFMA with two-term split
// (L=Lhi+Llo, h=hhi+hlo, 3 products; measured absmax 0.0093 vs 0.02 thr).
// 64x64 projection + tanh in post.
//
// R6 change (single variable vs R5): mm loads the wave's FULL 32KB A-slice
// (16 kb-blocks x hi/lo = 32 dwordx4, 128 VGPRs) right after the staging
// barrier, instead of a 4-deep ring. Entire A (64MB chip-wide) in flight;
// MFMA loop consumes progressively via compiler vmcnt(N).
//
// Pack layouts (lane-linear dwordx4 fragment loads):
//  Apack[rb][kb][l][8]: val = L[rb*16 + (l&15)][kb*32 + 8*(l>>4) + j]
//  Bpack[kb][cf][l][8]: val = h[kb*32 + 8*(l>>4) + j][cf*16 + (l&15)]
// mfma_f32_16x16x32_bf16: D[(l>>4)*4+r][l&15] (m89/m91 layout).

#define NN 4096
#define HH 64

typedef float  f32x4  __attribute__((ext_vector_type(4)));
typedef short  bf16x8 __attribute__((ext_vector_type(8)));

static __device__ __forceinline__ unsigned short bf16_bits(__hip_bfloat16 b) {
    union { __hip_bfloat16 b; unsigned short u; } cv; cv.b = b; return cv.u;
}

// ---------------------------------------------------------------------------
// Split + pack L -> Ahi/Alo (bf16 fragment-linear, 32MB each)
// grid 8192: rb = bid>>5 (256), kg = bid&31 (128-k group)
// ---------------------------------------------------------------------------
__global__ __launch_bounds__(256) void convert_L(
    const float* __restrict__ L, short* __restrict__ Ahi, short* __restrict__ Alo)
{
    __shared__ float T[16 * 132];
    const int t  = threadIdx.x;
    const int rb = blockIdx.x >> 5;
    const int kg = blockIdx.x & 31;

    {
        const int row = t >> 4;
        const int c4  = (t & 15) * 4;
        const float* src = L + (size_t)(rb * 16 + row) * NN + kg * 128;
        float4 v0 = *reinterpret_cast<const float4*>(src + c4);
        float4 v1 = *reinterpret_cast<const float4*>(src + c4 + 64);
        *reinterpret_cast<float4*>(&T[row * 132 + c4])      = v0;
        *reinterpret_cast<float4*>(&T[row * 132 + c4 + 64]) = v1;
    }
    __syncthreads();

    const int kbl = t >> 6;
    const int l   = t & 63;
    const int r   = l & 15, g = l >> 4;
    short hi8[8], lo8[8];
#pragma unroll
    for (int j = 0; j < 8; ++j) {
        const float v = T[r * 132 + kbl * 32 + g * 8 + j];
        __hip_bfloat16 bh = __float2bfloat16(v);
        const float vh = __bfloat162float(bh);
        __hip_bfloat16 bl = __float2bfloat16(v - vh);
        hi8[j] = (short)bf16_bits(bh);
        lo8[j] = (short)bf16_bits(bl);
    }
    const size_t off = ((size_t)(rb * 128 + kg * 4 + kbl) * 64 + l) * 8;
    *reinterpret_cast<bf16x8*>(Ahi + off) = *reinterpret_cast<bf16x8*>(hi8);
    *reinterpret_cast<bf16x8*>(Alo + off) = *reinterpret_cast<bf16x8*>(lo8);
}

// ---------------------------------------------------------------------------
// MFMA matmul: Gp[s] = partial (L @ h) over K-split s (K=512).
// grid 256 = 32 row-panels (128 rows) x 8 K-splits; 512 thr = 8 waves
// (2 waves/SIMD), wave w owns rowblock p*8+w. B-slice staged once in LDS
// (128KB). A: full 32KB wave-slice issued up-front (max MLP), consumed
// progressively. Two accumulator chains per cf.
// ---------------------------------------------------------------------------
__global__ __launch_bounds__(512) void gesn_mm(
    const short* __restrict__ Ahi, const short* __restrict__ Alo,
    const short* __restrict__ Bhi, const short* __restrict__ Blo,
    float* __restrict__ Gp)            // [8][4096][64]
{
    __shared__ short Bh_lds[16 * 4 * 64 * 8];   // 64KB  [kbl][cf][l][8]
    __shared__ short Bl_lds[16 * 4 * 64 * 8];   // 64KB

    const int t = threadIdx.x;
    const int w = t >> 6, l = t & 63;
    const int p = blockIdx.x >> 3;
    const int s = blockIdx.x & 7;
    const int rb = p * 8 + w;          // this wave's 16-row block
    const int kb0 = s * 16;

    // stage B-slice: 4096 bf16x8 frags per array, 8 per thread each
    {
        const short* srcH = Bhi + (size_t)kb0 * 4 * 64 * 8;
        const short* srcL = Blo + (size_t)kb0 * 4 * 64 * 8;
#pragma unroll
        for (int q = 0; q < 8; ++q) {
            const int idx = (q * 512 + t) * 8;
            *reinterpret_cast<bf16x8*>(&Bh_lds[idx]) =
                *reinterpret_cast<const bf16x8*>(srcH + idx);
            *reinterpret_cast<bf16x8*>(&Bl_lds[idx]) =
                *reinterpret_cast<const bf16x8*>(srcL + idx);
        }
    }
    __syncthreads();

    // issue the wave's ENTIRE A-slice (32 loads, 128 VGPRs) -- after the
    // barrier so the barrier's vmcnt(0) drain doesn't serialize them.
    const size_t abase = ((size_t)(rb * 128 + kb0) * 64 + l) * 8;
    bf16x8 aH[16], aL[16];
#pragma unroll
    for (int q = 0; q < 16; ++q) {
        aH[q] = *reinterpret_cast<const bf16x8*>(Ahi + abase + (size_t)q * 512);
        aL[q] = *reinterpret_cast<const bf16x8*>(Alo + abase + (size_t)q * 512);
    }

    f32x4 accP[4] = {};                // aH*bH
    f32x4 accQ[4] = {};                // aH*bL + aL*bH

#pragma unroll
    for (int kbl = 0; kbl < 16; ++kbl) {
        bf16x8 bH[4], bL[4];
#pragma unroll
        for (int cf = 0; cf < 4; ++cf) {
            const int idx = ((kbl * 4 + cf) * 64 + l) * 8;
            bH[cf] = *reinterpret_cast<const bf16x8*>(&Bh_lds[idx]);
            bL[cf] = *reinterpret_cast<const bf16x8*>(&Bl_lds[idx]);
        }
#pragma unroll
        for (int cf = 0; cf < 4; ++cf) {
            accP[cf] = __builtin_amdgcn_mfma_f32_16x16x32_bf16(
                aH[kbl], bH[cf], accP[cf], 0, 0, 0);
            accQ[cf] = __builtin_amdgcn_mfma_f32_16x16x32_bf16(
                aH[kbl], bL[cf], accQ[cf], 0, 0, 0);
            accQ[cf] = __builtin_amdgcn_mfma_f32_16x16x32_bf16(
                aL[kbl], bH[cf], accQ[cf], 0, 0, 0);
        }
    }

    float* g = Gp + (size_t)s * NN * HH;
    const int col0  = l & 15;
    const int rbase = (l >> 4) * 4;
#pragma unroll
    for (int cf = 0; cf < 4; ++cf)
#pragma unroll
        for (int r = 0; r < 4; ++r)
            g[(size_t)(rb * 16 + rbase + r) * HH + cf * 16 + col0]
                = accP[cf][r] + accQ[cf][r];
}

// ---------------------------------------------------------------------------
// Post: z = (wiu_in?) + (reduce_s Gsrc) @ W^T ; h = tanh(z)
//   nsplit==0: Gsrc is x [4096][64] (computes wiu), else Gp [8][4096][64].
// grid 256 x 16 rows, 256 threads. bf16 pack via small LDS transpose tile.
// ---------------------------------------------------------------------------
__global__ __launch_bounds__(256) void gesn_post(
    const float* __restrict__ Gsrc, int nsplit,
    const float* __restrict__ wiu_in, float* __restrict__ wiu_out,
    const float* __restrict__ W,                  // [64][64]
    float* __restrict__ hf32,
    short* __restrict__ Bhi, short* __restrict__ Blo,
    float* __restrict__ out2, int outc0)
{
    __shared__ float W_lds[64 * 65];
    __shared__ float G_lds[16 * 68];
    __shared__ unsigned short Hi_lds[16][66];
    __shared__ unsigned short Lo_lds[16][66];
    const int t = threadIdx.x;

    {   // W load
        const int j  = t >> 2;
        const int k0 = (t & 3) << 4;
#pragma unroll
        for (int q = 0; q < 16; ++q)
            W_lds[j * 65 + k0 + q] = W[j * 64 + k0 + q];
    }
    const int r0 = blockIdx.x * 16;

    // load(+reduce) G: 16x64 f32 = 256 float4, one per thread
    {
        const int row = t >> 4;
        const int c4  = (t & 15) * 4;
        float4 sum;
        if (nsplit == 0) {
            sum = *reinterpret_cast<const float4*>(
                Gsrc + (size_t)(r0 + row) * HH + c4);
        } else {
            sum = make_float4(0.f, 0.f, 0.f, 0.f);
            for (int sidx = 0; sidx < nsplit; ++sidx) {
                const float4 v = *reinterpret_cast<const float4*>(
                    Gsrc + (size_t)sidx * NN * HH + (size_t)(r0 + row) * HH + c4);
                sum.x += v.x; sum.y += v.y; sum.z += v.z; sum.w += v.w;
            }
        }
        *reinterpret_cast<float4*>(&G_lds[row * 68 + c4]) = sum;
    }
    __syncthreads();

    const int j  = t & 63;
    const int ig = t >> 6;
#pragma unroll
    for (int rr = 0; rr < 4; ++rr) {
        const int i = ig * 4 + rr;            // 0..15
        float z = wiu_in ? wiu_in[(size_t)(r0 + i) * HH + j] : 0.f;
#pragma unroll
        for (int m = 0; m < 64; ++m)
            z = fmaf(G_lds[i * 68 + m], W_lds[j * 65 + m], z);
        if (wiu_out) wiu_out[(size_t)(r0 + i) * HH + j] = z;
        const float hv = tanhf(z);
        hf32[(size_t)(r0 + i) * HH + j] = hv;
        if (out2) out2[(size_t)(r0 + i) * 128 + outc0 + j] = hv;
        __hip_bfloat16 bh = __float2bfloat16(hv);
        const float vh = __bfloat162float(bh);
        __hip_bfloat16 bl = __float2bfloat16(hv - vh);
        Hi_lds[i][j] = bf16_bits(bh);
        Lo_lds[i][j] = bf16_bits(bl);
    }
    __syncthreads();

    // pack: 128 threads, each owns 8 consecutive rows at one column
    if (t < 128) {
        const int j2     = t & 63;
        const int glocal = t >> 6;                 // 0..1
        const int kb     = r0 >> 5;
        const int gg     = ((r0 & 31) >> 3) + glocal;
        const int cf     = j2 >> 4;
        const int lane   = gg * 16 + (j2 & 15);
        short hi8[8], lo8[8];
#pragma unroll
        for (int jj = 0; jj < 8; ++jj) {
            const int i = glocal * 8 + jj;
            hi8[jj] = (short)Hi_lds[i][j2];
            lo8[jj] = (short)Lo_lds[i][j2];
        }
        const size_t off = ((size_t)(kb * 4 + cf) * 64 + lane) * 8;
        *reinterpret_cast<bf16x8*>(Bhi + off) = *reinterpret_cast<bf16x8*>(hi8);
        *reinterpret_cast<bf16x8*>(Blo + off) = *reinterpret_cast<bf16x8*>(lo8);
    }
}

// ---------------------------------------------------------------------------
// Fallback f32 path (round-0 kernels, small-ws safety)
// ---------------------------------------------------------------------------
__global__ __launch_bounds__(256) void gesn_input_kernel(
    const float* __restrict__ x, const float* __restrict__ W,
    float* __restrict__ wiu, float* __restrict__ h)
{
    __shared__ float W_lds[64 * 65];
    __shared__ float x_lds[256];
    const int t = threadIdx.x;
    {
        const int j  = t >> 2;
        const int k0 = (t & 3) << 4;
#pragma unroll
        for (int q = 0; q < 16; ++q)
            W_lds[j * 65 + k0 + q] = W[j * 64 + k0 + q];
    }
    const int i0 = blockIdx.x * 4;
    x_lds[t] = x[i0 * 64 + t];
    __syncthreads();
    const int j = t & 63, i = t >> 6;
    float z = 0.f;
#pragma unroll
    for (int k = 0; k < 64; ++k)
        z = fmaf(x_lds[i * 64 + k], W_lds[j * 65 + k], z);
    const int gidx = (i0 + i) * 64 + j;
    wiu[gidx] = z;
    h[gidx]   = tanhf(z);
}

__global__ __launch_bounds__(256) void gesn_iter_kernel(
    const float* __restrict__ L, const float* __restrict__ h_in,
    const float* __restrict__ wiu, const float* __restrict__ W,
    float* __restrict__ h_out, float* __restrict__ out2, int out_col0)
{
    __shared__ float h_lds[64 * 64];
    __shared__ float L_lds[16 * 68];
    __shared__ float G_lds[16 * 68];
    __shared__ float W_lds[64 * 65];
    const int t = threadIdx.x;
    {
        const int j  = t >> 2;
        const int k0 = (t & 3) << 4;
#pragma unroll
        for (int q = 0; q < 16; ++q)
            W_lds[j * 65 + k0 + q] = W[j * 64 + k0 + q];
    }
    const int r0 = blockIdx.x * 16;
    const int p  = t >> 5;
    const int c0 = (t & 31) * 2;
    float acc00 = 0.f, acc01 = 0.f, acc10 = 0.f, acc11 = 0.f;
    const int lr = t >> 4;
    const int lc = (t & 15) * 4;
    for (int kb = 0; kb < 64; ++kb) {
        __syncthreads();
        const float4 lv = *reinterpret_cast<const float4*>(
            &L[(size_t)(r0 + lr) * 4096 + kb * 64 + lc]);
        *reinterpret_cast<float4*>(&L_lds[lr * 68 + lc]) = lv;
        const float4* hsrc = reinterpret_cast<const float4*>(h_in + kb * 4096);
        float4* hdst = reinterpret_cast<float4*>(h_lds);
#pragma unroll
        for (int q = 0; q < 4; ++q)
            hdst[t + 256 * q] = hsrc[t + 256 * q];
        __syncthreads();
#pragma unroll
        for (int kk = 0; kk < 64; ++kk) {
            const float  lv0 = L_lds[(2 * p) * 68 + kk];
            const float  lv1 = L_lds[(2 * p + 1) * 68 + kk];
            const float2 hv  = *reinterpret_cast<const float2*>(&h_lds[kk * 64 + c0]);
            acc00 = fmaf(lv0, hv.x, acc00);
            acc01 = fmaf(lv0, hv.y, acc01);
            acc10 = fmaf(lv1, hv.x, acc10);
            acc11 = fmaf(lv1, hv.y, acc11);
        }
    }
    G_lds[(2 * p) * 68 + c0]         = acc00;
    G_lds[(2 * p) * 68 + c0 + 1]     = acc01;
    G_lds[(2 * p + 1) * 68 + c0]     = acc10;
    G_lds[(2 * p + 1) * 68 + c0 + 1] = acc11;
    __syncthreads();
    const int j  = t & 63;
    const int iw = t >> 6;
#pragma unroll
    for (int rr = 0; rr < 4; ++rr) {
        const int i = iw * 4 + rr;
        float z = wiu[(size_t)(r0 + i) * 64 + j];
#pragma unroll
        for (int m = 0; m < 64; ++m)
            z = fmaf(G_lds[i * 68 + m], W_lds[j * 65 + m], z);
        const float hv = tanhf(z);
        h_out[(size_t)(r0 + i) * 64 + j] = hv;
        if (out2) out2[(size_t)(r0 + i) * 128 + out_col0 + j] = hv;
    }
}

// ---------------------------------------------------------------------------
extern "C" void kernel_launch(void* const* d_in, const int* in_sizes, int n_in,
                              void* d_out, int out_size, void* d_ws, size_t ws_size,
                              hipStream_t stream) {
    const float* X    = (const float*)d_in[0];
    const float* L    = (const float*)d_in[1];
    const float* Wih0 = (const float*)d_in[2];
    const float* Whh0 = (const float*)d_in[3];
    const float* Wih1 = (const float*)d_in[4];
    const float* Whh1 = (const float*)d_in[5];
    float* out = (float*)d_out;
    char* ws = (char*)d_ws;

    const size_t MB = 1024 * 1024;
    const size_t need = 76 * MB;

    if (ws_size >= need) {
        short* Ahi = (short*)(ws);                 // 32 MB
        short* Alo = (short*)(ws + 32 * MB);       // 32 MB
        short* Bhi = (short*)(ws + 64 * MB);       // 0.5 MB
        short* Blo = (short*)(ws + 64 * MB + 512 * 1024);
        float* wiu = (float*)(ws + 65 * MB);       // 1 MB
        float* hA  = (float*)(ws + 66 * MB);       // 1 MB
        float* hB  = (float*)(ws + 67 * MB);       // 1 MB
        float* Gp  = (float*)(ws + 68 * MB);       // 8 MB

        convert_L<<<8192, 256, 0, stream>>>(L, Ahi, Alo);

        for (int layer = 0; layer < 2; ++layer) {
            const float* x   = layer ? hA : X;
            const float* Wih = layer ? Wih1 : Wih0;
            const float* Whh = layer ? Whh1 : Whh0;
            float* hcur = layer ? hB : hA;

            // iter 1: wiu = x@Wih^T; h = tanh(wiu); pack h
            gesn_post<<<256, 256, 0, stream>>>(x, 0, nullptr, wiu, Wih,
                                               hcur, Bhi, Blo, nullptr, 0);
            // iters 2..10
            for (int it = 0; it < 9; ++it) {
                gesn_mm<<<256, 512, 0, stream>>>(Ahi, Alo, Bhi, Blo, Gp);
                float* o2 = (it == 8) ? out : nullptr;
                gesn_post<<<256, 256, 0, stream>>>(Gp, 8, wiu, nullptr, Whh,
                                                   hcur, Bhi, Blo, o2, layer * 64);
            }
        }
    } else {
        // f32 fallback (verified round-0 path)
        float* wiu = (float*)(ws);
        float* hA  = (float*)(ws + (1u << 20));
        float* hB  = (float*)(ws + (2u << 20));
        for (int layer = 0; layer < 2; ++layer) {
            const float* x   = layer ? hB : X;
            const float* Wih = layer ? Wih1 : Wih0;
            const float* Whh = layer ? Whh1 : Whh0;
            gesn_input_kernel<<<1024, 256, 0, stream>>>(x, Wih, wiu, hA);
            float* cur = hA;
            float* nxt = hB;
            for (int it = 0; it < 9; ++it) {
                float* o2 = (it == 8) ? out : nullptr;
                gesn_iter_kernel<<<256, 256, 0, stream>>>(L, cur, wiu, Whh, nxt,
                                                          o2, layer * 64);
                float* tmp = cur; cur = nxt; nxt = tmp;
            }
        }
    }
}